// Round 1
// baseline (17762.936 us; speedup 1.0000x reference)
//
#include <hip/hip_runtime.h>
#include <hip/hip_cooperative_groups.h>

namespace cg = cooperative_groups;

#define Bn 512
#define Tn 256
#define Fn 128
#define Hn 512
#define Gn 2048
#define KIE 20   // 640/32 k-iters (encoder: [x|h], K=640)
#define KID 16   // 512/32 k-iters (decoder: h only, K=512)

typedef __attribute__((ext_vector_type(8))) __bf16 bf16x8;
typedef __attribute__((ext_vector_type(4))) float floatx4;

__device__ __forceinline__ unsigned short f2bf_u16(float f) {
  union { float f; unsigned u; } v; v.f = f;
  unsigned r = v.u + 0x7FFFu + ((v.u >> 16) & 1u);   // RNE
  return (unsigned short)(r >> 16);
}

// ---- pack encoder weights [x|h] -> B-fragment order [nt][ki][lane][8] ----
__global__ void pack_enc_k(const float* __restrict__ Wih, const float* __restrict__ Whh,
                           unsigned short* __restrict__ Bpe) {
  int id = blockIdx.x;              // nt*KIE + ki, 128*20 blocks
  int nt = id / KIE, ki = id % KIE;
  int l = threadIdx.x;
  int n = nt * 16 + (l & 15);
  int kb = ki * 32 + (l >> 4) * 8;
  __align__(16) unsigned short o[8];
#pragma unroll
  for (int j = 0; j < 8; ++j) {
    int k = kb + j;
    float v = (k < Fn) ? Wih[n * Fn + k] : Whh[n * Hn + (k - Fn)];
    o[j] = f2bf_u16(v);
  }
  *(uint4*)(Bpe + (size_t)(id * 64 + l) * 8) = *(uint4*)o;
}

// ---- pack decoder combined weights (W_hh + W_ih@Wo) -> fragment order ----
__global__ void pack_dec_k(const float* __restrict__ Wih, const float* __restrict__ Whh,
                           const float* __restrict__ Wo, unsigned short* __restrict__ Bpd) {
  int id = blockIdx.x;              // nt*KID + ki, 128*16 blocks
  int nt = id / KID, ki = id % KID;
  int l = threadIdx.x;
  int n = nt * 16 + (l & 15);
  int kb = ki * 32 + (l >> 4) * 8;
  float acc[8];
#pragma unroll
  for (int j = 0; j < 8; ++j) acc[j] = Whh[n * Hn + kb + j];
  for (int f = 0; f < Fn; ++f) {
    float wf = Wih[n * Fn + f];
    const float* wo = Wo + f * Hn + kb;
#pragma unroll
    for (int j = 0; j < 8; ++j) acc[j] += wf * wo[j];
  }
  __align__(16) unsigned short o[8];
#pragma unroll
  for (int j = 0; j < 8; ++j) o[j] = f2bf_u16(acc[j]);
  *(uint4*)(Bpd + (size_t)(id * 64 + l) * 8) = *(uint4*)o;
}

// ---- pack Wo (for y = h@Wo.T) -> fragment order [ft][ki][lane][8] ----
__global__ void pack_wo_k(const float* __restrict__ Wo, unsigned short* __restrict__ Bpw) {
  int id = blockIdx.x;              // ft*KID + ki, 8*16 blocks
  int ft = id / KID, ki = id % KID;
  int l = threadIdx.x;
  int f = ft * 16 + (l & 15);
  int kb = ki * 32 + (l >> 4) * 8;
  __align__(16) unsigned short o[8];
#pragma unroll
  for (int j = 0; j < 8; ++j) o[j] = f2bf_u16(Wo[f * Hn + kb + j]);
  *(uint4*)(Bpw + (size_t)(id * 64 + l) * 8) = *(uint4*)o;
}

// ---- biases: benc = eb_ih+eb_hh ; bdec = db_ih+db_hh + dW_ih@bo ----
__global__ void bias_k(const float* __restrict__ ebih, const float* __restrict__ ebhh,
                       const float* __restrict__ dbih, const float* __restrict__ dbhh,
                       const float* __restrict__ dWih, const float* __restrict__ bo,
                       float* __restrict__ benc, float* __restrict__ bdec) {
  int n = blockIdx.x * blockDim.x + threadIdx.x;  // 2048
  benc[n] = ebih[n] + ebhh[n];
  float a = dbih[n] + dbhh[n];
  for (int f = 0; f < Fn; ++f) a += dWih[n * Fn + f] * bo[f];
  bdec[n] = a;
}

// ---- persistent LSTM encoder-decoder: 256 wgs x 512 thr, cooperative ----
__global__ __launch_bounds__(512, 2) void lstm_persist(
    const float* __restrict__ ts,
    const unsigned short* __restrict__ Bpe,
    const unsigned short* __restrict__ Bpd,
    const unsigned short* __restrict__ Bpw,
    const float* __restrict__ benc,
    const float* __restrict__ bdec,
    const float* __restrict__ bo,
    unsigned short* __restrict__ Hg,   // [2][512][512] bf16 double buffer
    float* __restrict__ out)           // [512][256][128] fp32
{
  cg::grid_group grid = cg::this_grid();
  const int wg = blockIdx.x;
  const int mg = wg >> 4, ns = wg & 15;
  const int b0 = mg * 32, j0 = ns * 32;
  const int tid = threadIdx.x;
  const int w = tid >> 6, l = tid & 63;
  const int l15 = l & 15, q = l >> 4;

  __shared__ __align__(16) unsigned short A_lds[32 * 648];  // 32 rows x 640 (+8 pad)
  __shared__ float gates_lds[4][32][34];
  __shared__ float bias_lds[4][32];

  // zero Hg[0] (each wg zeros its 1024-element slice)
  {
    uint4 z; z.x = z.y = z.z = z.w = 0u;
    if (tid < 128) ((uint4*)(Hg + (size_t)wg * 1024))[tid] = z;
  }
  if (tid < 128) bias_lds[tid >> 5][tid & 31] = benc[(tid >> 5) * Hn + j0 + (tid & 31)];

  float c0 = 0.f, c1 = 0.f;
  // wave w owns global gate n-tile nt (gate g = w>>1, 16-col sub = w&1), both 16-row strips
  const int nt = (w >> 1) * 32 + ns * 2 + (w & 1);
  const int g_ = w >> 1, jsub = (w & 1) * 16;

  grid.sync();

  int cur = 0;
  // ================= encoder =================
  for (int s = 0; s < Tn; ++s) {
    { // stage x_t -> A[:, 0:128] (fp32 -> bf16 RNE)
      int b = tid >> 4, k8 = (tid & 15) * 8;
      const float* src = ts + (size_t)(b0 + b) * (Tn * Fn) + (size_t)s * Fn + k8;
      float4 x0 = *(const float4*)src;
      float4 x1 = *(const float4*)(src + 4);
      __align__(16) unsigned short t8[8];
      t8[0] = f2bf_u16(x0.x); t8[1] = f2bf_u16(x0.y); t8[2] = f2bf_u16(x0.z); t8[3] = f2bf_u16(x0.w);
      t8[4] = f2bf_u16(x1.x); t8[5] = f2bf_u16(x1.y); t8[6] = f2bf_u16(x1.z); t8[7] = f2bf_u16(x1.w);
      *(uint4*)&A_lds[b * 648 + k8] = *(uint4*)t8;
    }
    { // stage h -> A[:, 128:640]
      int b = tid >> 4, kc = (tid & 15) * 32;
      const uint4* src = (const uint4*)(Hg + (size_t)cur * Bn * Hn + (size_t)(b0 + b) * Hn + kc);
      uint4* dst = (uint4*)&A_lds[b * 648 + 128 + kc];
#pragma unroll
      for (int i = 0; i < 4; ++i) dst[i] = src[i];
    }
    __syncthreads();

    floatx4 acc0 = {0.f, 0.f, 0.f, 0.f}, acc1 = {0.f, 0.f, 0.f, 0.f};
    const bf16x8* Bp = (const bf16x8*)Bpe + (size_t)nt * KIE * 64 + l;
    const unsigned short* Ar0 = &A_lds[l15 * 648 + q * 8];
    const unsigned short* Ar1 = &A_lds[(16 + l15) * 648 + q * 8];
#pragma unroll
    for (int k = 0; k < KIE; ++k) {
      bf16x8 bfr = Bp[k * 64];
      bf16x8 a0 = *(const bf16x8*)(Ar0 + k * 32);
      bf16x8 a1 = *(const bf16x8*)(Ar1 + k * 32);
      acc0 = __builtin_amdgcn_mfma_f32_16x16x32_bf16(a0, bfr, acc0, 0, 0, 0);
      acc1 = __builtin_amdgcn_mfma_f32_16x16x32_bf16(a1, bfr, acc1, 0, 0, 0);
    }
#pragma unroll
    for (int r = 0; r < 4; ++r) {
      gates_lds[g_][q * 4 + r][jsub + l15] = acc0[r];
      gates_lds[g_][16 + q * 4 + r][jsub + l15] = acc1[r];
    }
    __syncthreads();

    unsigned short* Hnxt = Hg + (size_t)(cur ^ 1) * Bn * Hn;
#pragma unroll
    for (int p = 0; p < 2; ++p) {
      int idx = tid + p * 512;
      int b = idx >> 5, j = idx & 31;
      float gi = gates_lds[0][b][j] + bias_lds[0][j];
      float gf = gates_lds[1][b][j] + bias_lds[1][j];
      float gg = gates_lds[2][b][j] + bias_lds[2][j];
      float go = gates_lds[3][b][j] + bias_lds[3][j];
      float c = p ? c1 : c0;
      c = (1.f / (1.f + expf(-gf))) * c + (1.f / (1.f + expf(-gi))) * tanhf(gg);
      float h = (1.f / (1.f + expf(-go))) * tanhf(c);
      if (p) c1 = c; else c0 = c;
      Hnxt[(size_t)(b0 + b) * Hn + j0 + j] = f2bf_u16(h);
    }
    grid.sync();
    cur ^= 1;
  }

  // ================= decoder =================
  if (tid < 128) bias_lds[tid >> 5][tid & 31] = bdec[(tid >> 5) * Hn + j0 + (tid & 31)];
  c0 = c1 = 0.f;   // reference restarts c at zero for the decoder
  const bool do_y = (ns < 8) && (w < 2);
  const bf16x8* Bw = (const bf16x8*)Bpw + (size_t)(ns & 7) * KID * 64 + l;

  for (int s = 0; s < Tn; ++s) {
    { // stage h -> A[:, 0:512]
      int b = tid >> 4, kc = (tid & 15) * 32;
      const uint4* src = (const uint4*)(Hg + (size_t)cur * Bn * Hn + (size_t)(b0 + b) * Hn + kc);
      uint4* dst = (uint4*)&A_lds[b * 648 + kc];
#pragma unroll
      for (int i = 0; i < 4; ++i) dst[i] = src[i];
    }
    __syncthreads();

    floatx4 acc0 = {0.f, 0.f, 0.f, 0.f}, acc1 = {0.f, 0.f, 0.f, 0.f}, accy = {0.f, 0.f, 0.f, 0.f};
    const bf16x8* Bp = (const bf16x8*)Bpd + (size_t)nt * KID * 64 + l;
    const unsigned short* Ar0 = &A_lds[l15 * 648 + q * 8];
    const unsigned short* Ar1 = &A_lds[(16 + l15) * 648 + q * 8];
#pragma unroll
    for (int k = 0; k < KID; ++k) {
      bf16x8 bfr = Bp[k * 64];
      bf16x8 a0 = *(const bf16x8*)(Ar0 + k * 32);
      bf16x8 a1 = *(const bf16x8*)(Ar1 + k * 32);
      acc0 = __builtin_amdgcn_mfma_f32_16x16x32_bf16(a0, bfr, acc0, 0, 0, 0);
      acc1 = __builtin_amdgcn_mfma_f32_16x16x32_bf16(a1, bfr, acc1, 0, 0, 0);
      if (do_y) {
        bf16x8 bw = Bw[k * 64];
        accy = __builtin_amdgcn_mfma_f32_16x16x32_bf16(w ? a1 : a0, bw, accy, 0, 0, 0);
      }
    }
#pragma unroll
    for (int r = 0; r < 4; ++r) {
      gates_lds[g_][q * 4 + r][jsub + l15] = acc0[r];
      gates_lds[g_][16 + q * 4 + r][jsub + l15] = acc1[r];
    }
    if (do_y) { // emit y = h@Wo.T + bo at flipped time index (pre-update h)
      int f = (ns & 7) * 16 + l15;
      float bof = bo[f];
      int brow = w * 16 + q * 4;
      size_t tbase = (size_t)(Tn - 1 - s) * Fn + f;
#pragma unroll
      for (int r = 0; r < 4; ++r)
        out[(size_t)(b0 + brow + r) * (Tn * Fn) + tbase] = accy[r] + bof;
    }
    __syncthreads();

    unsigned short* Hnxt = Hg + (size_t)(cur ^ 1) * Bn * Hn;
#pragma unroll
    for (int p = 0; p < 2; ++p) {
      int idx = tid + p * 512;
      int b = idx >> 5, j = idx & 31;
      float gi = gates_lds[0][b][j] + bias_lds[0][j];
      float gf = gates_lds[1][b][j] + bias_lds[1][j];
      float gg = gates_lds[2][b][j] + bias_lds[2][j];
      float go = gates_lds[3][b][j] + bias_lds[3][j];
      float c = p ? c1 : c0;
      c = (1.f / (1.f + expf(-gf))) * c + (1.f / (1.f + expf(-gi))) * tanhf(gg);
      float h = (1.f / (1.f + expf(-go))) * tanhf(c);
      if (p) c1 = c; else c0 = c;
      Hnxt[(size_t)(b0 + b) * Hn + j0 + j] = f2bf_u16(h);
    }
    grid.sync();
    cur ^= 1;
  }
}

extern "C" void kernel_launch(void* const* d_in, const int* in_sizes, int n_in,
                              void* d_out, int out_size, void* d_ws, size_t ws_size,
                              hipStream_t stream) {
  const float* ts   = (const float*)d_in[0];
  const float* eWih = (const float*)d_in[1];
  const float* eWhh = (const float*)d_in[2];
  const float* ebih = (const float*)d_in[3];
  const float* ebhh = (const float*)d_in[4];
  const float* dWih = (const float*)d_in[5];
  const float* dWhh = (const float*)d_in[6];
  const float* dbih = (const float*)d_in[7];
  const float* dbhh = (const float*)d_in[8];
  const float* Wo   = (const float*)d_in[9];
  const float* bo   = (const float*)d_in[10];
  float* outp = (float*)d_out;

  char* ws = (char*)d_ws;
  unsigned short* Bpe  = (unsigned short*)(ws);                 // 2048*640*2   = 2,621,440 B
  unsigned short* Bpd  = (unsigned short*)(ws + 2621440);       // 2048*512*2   = 2,097,152 B
  unsigned short* Bpw  = (unsigned short*)(ws + 4718592);       // 128*512*2    =   131,072 B
  float*          benc = (float*)(ws + 4849664);                // 2048*4
  float*          bdec = (float*)(ws + 4857856);                // 2048*4
  unsigned short* Hg   = (unsigned short*)(ws + 4866048);       // 2*512*512*2  = 1,048,576 B

  pack_enc_k<<<128 * KIE, 64, 0, stream>>>(eWih, eWhh, Bpe);
  pack_dec_k<<<128 * KID, 64, 0, stream>>>(dWih, dWhh, Wo, Bpd);
  pack_wo_k<<<8 * KID, 64, 0, stream>>>(Wo, Bpw);
  bias_k<<<8, 256, 0, stream>>>(ebih, ebhh, dbih, dbhh, dWih, bo, benc, bdec);

  void* args[] = {&ts, &Bpe, &Bpd, &Bpw, &benc, &bdec, &bo, &Hg, &outp};
  hipLaunchCooperativeKernel(reinterpret_cast<void*>(lstm_persist),
                             dim3(256), dim3(512), args, 0, stream);
}

// Round 2
// 3577.411 us; speedup vs baseline: 4.9653x; 4.9653x over previous
//
#include <hip/hip_runtime.h>

#define Bn 512
#define Tn 256
#define Fn 128
#define Hn 512
#define KIE 20   // 640/32 k-iters (encoder: [x|h], K=640)
#define KID 16   // 512/32 k-iters (decoder: h only, K=512)
#define NWG 256

typedef __attribute__((ext_vector_type(8))) __bf16 bf16x8;
typedef __attribute__((ext_vector_type(4))) float floatx4;

__device__ __forceinline__ unsigned short f2bf_u16(float f) {
  union { float f; unsigned u; } v; v.f = f;
  unsigned r = v.u + 0x7FFFu + ((v.u >> 16) & 1u);   // RNE
  return (unsigned short)(r >> 16);
}

__device__ __forceinline__ float sigm(float x) { return 1.f / (1.f + expf(-x)); }

// ---- pack encoder weights [x|h] -> B-fragment order [nt][ki][lane][8] ----
__global__ void pack_enc_k(const float* __restrict__ Wih, const float* __restrict__ Whh,
                           unsigned short* __restrict__ Bpe) {
  int id = blockIdx.x;              // nt*KIE + ki, 128*20 blocks
  int nt = id / KIE, ki = id % KIE;
  int l = threadIdx.x;
  int n = nt * 16 + (l & 15);
  int kb = ki * 32 + (l >> 4) * 8;
  __align__(16) unsigned short o[8];
#pragma unroll
  for (int j = 0; j < 8; ++j) {
    int k = kb + j;
    float v = (k < Fn) ? Wih[n * Fn + k] : Whh[n * Hn + (k - Fn)];
    o[j] = f2bf_u16(v);
  }
  *(uint4*)(Bpe + (size_t)(id * 64 + l) * 8) = *(uint4*)o;
}

// ---- pack decoder combined weights (W_hh + W_ih@Wo) -> fragment order ----
__global__ void pack_dec_k(const float* __restrict__ Wih, const float* __restrict__ Whh,
                           const float* __restrict__ Wo, unsigned short* __restrict__ Bpd) {
  int id = blockIdx.x;              // nt*KID + ki, 128*16 blocks
  int nt = id / KID, ki = id % KID;
  int l = threadIdx.x;
  int n = nt * 16 + (l & 15);
  int kb = ki * 32 + (l >> 4) * 8;
  float acc[8];
#pragma unroll
  for (int j = 0; j < 8; ++j) acc[j] = Whh[n * Hn + kb + j];
  for (int f = 0; f < Fn; ++f) {
    float wf = Wih[n * Fn + f];
    const float* wo = Wo + f * Hn + kb;
#pragma unroll
    for (int j = 0; j < 8; ++j) acc[j] += wf * wo[j];
  }
  __align__(16) unsigned short o[8];
#pragma unroll
  for (int j = 0; j < 8; ++j) o[j] = f2bf_u16(acc[j]);
  *(uint4*)(Bpd + (size_t)(id * 64 + l) * 8) = *(uint4*)o;
}

// ---- pack Wo (for y = h@Wo.T) -> fragment order [ft][ki][lane][8] ----
__global__ void pack_wo_k(const float* __restrict__ Wo, unsigned short* __restrict__ Bpw) {
  int id = blockIdx.x;              // ft*KID + ki, 8*16 blocks
  int ft = id / KID, ki = id % KID;
  int l = threadIdx.x;
  int f = ft * 16 + (l & 15);
  int kb = ki * 32 + (l >> 4) * 8;
  __align__(16) unsigned short o[8];
#pragma unroll
  for (int j = 0; j < 8; ++j) o[j] = f2bf_u16(Wo[f * Hn + kb + j]);
  *(uint4*)(Bpw + (size_t)(id * 64 + l) * 8) = *(uint4*)o;
}

// ---- biases: benc = eb_ih+eb_hh ; bdec = db_ih+db_hh + dW_ih@bo ----
__global__ void bias_k(const float* __restrict__ ebih, const float* __restrict__ ebhh,
                       const float* __restrict__ dbih, const float* __restrict__ dbhh,
                       const float* __restrict__ dWih, const float* __restrict__ bo,
                       float* __restrict__ benc, float* __restrict__ bdec) {
  int n = blockIdx.x * blockDim.x + threadIdx.x;  // 2048
  benc[n] = ebih[n] + ebhh[n];
  float a = dbih[n] + dbhh[n];
  for (int f = 0; f < Fn; ++f) a += dWih[n * Fn + f] * bo[f];
  bdec[n] = a;
}

// ---- init: zero Hg buffer 0 (512 KB) + barrier counters ----
__global__ void init_k(unsigned long long* __restrict__ Hg0, unsigned* __restrict__ bar) {
  int i = blockIdx.x * 256 + threadIdx.x;   // 256 blocks x 256 thr = 65536 = 512KB/8
  Hg0[i] = 0ULL;
  if (i < 512) bar[i] = 0u;
}

// ---- 2-level monotonic grid barrier over L3 (relaxed agent atomics, no L2 flush) ----
// bar[(wg&7)*32]: 8 group counters (128B apart); bar[256]: top counter (+8/phase).
__device__ __forceinline__ void gbar(unsigned* bar, int wg, unsigned phase) {
  __syncthreads();   // drains vmcnt: all sc1 h-stores acked at L3 before arrival
  if (threadIdx.x == 0) {
    unsigned old = __hip_atomic_fetch_add(&bar[(wg & 7) * 32], 1u,
                     __ATOMIC_RELAXED, __HIP_MEMORY_SCOPE_AGENT);
    if (old == phase * 32u - 1u)
      __hip_atomic_fetch_add(&bar[256], 1u, __ATOMIC_RELAXED, __HIP_MEMORY_SCOPE_AGENT);
    while (__hip_atomic_load(&bar[256], __ATOMIC_RELAXED, __HIP_MEMORY_SCOPE_AGENT)
           < phase * 8u) {}
  }
  __syncthreads();
}

// ---- persistent LSTM encoder-decoder: 256 wgs x 512 thr, custom barrier ----
__global__ __launch_bounds__(512, 2) void lstm_persist(
    const float* __restrict__ ts,
    const unsigned short* __restrict__ Bpe,
    const unsigned short* __restrict__ Bpd,
    const unsigned short* __restrict__ Bpw,
    const float* __restrict__ benc,
    const float* __restrict__ bdec,
    const float* __restrict__ bo,
    unsigned short* __restrict__ Hg,   // [2][512][512] bf16 double buffer (sc1 access only)
    unsigned* __restrict__ bar,
    float* __restrict__ out)           // [512][256][128] fp32
{
  const int wg = blockIdx.x;
  const int mg = wg >> 4, ns = wg & 15;
  const int b0 = mg * 32, j0 = ns * 32;
  const int tid = threadIdx.x;
  const int w = tid >> 6, l = tid & 63;
  const int l15 = l & 15, q = l >> 4;
  const int g_ = w >> 1, rh = w & 1;     // wave = (gate, row-half)

  __shared__ __align__(16) unsigned short A_lds[32 * 648];       // 32 rows x 640 (+8 pad)
  __shared__ __align__(16) float gates_lds[4][32][34];
  __shared__ float bias_lds[4][32];
  __shared__ __align__(16) unsigned short Bw_lds[KID * 64 * 8];  // 16 KB Wo slice

  const int nt0 = g_ * 32 + ns * 2;      // first of this wave's two 16-col gate tiles
  const int sb = tid >> 4;               // staging row 0..31
  const int sk = tid & 15;               // staging col group / epilogue j-pair

  // ---- preload encoder B tiles into registers (2 tiles x 20 k-iters = 160 VGPRs) ----
  bf16x8 Bq0[KIE], Bq1[KIE];
  {
    const bf16x8* p = (const bf16x8*)Bpe + (size_t)nt0 * (KIE * 64) + l;
#pragma unroll
    for (int k = 0; k < KIE; ++k) { Bq0[k] = p[k * 64]; Bq1[k] = p[(KIE + k) * 64]; }
  }
  if (tid < 128) bias_lds[tid >> 5][tid & 31] = benc[(tid >> 5) * Hn + j0 + (tid & 31)];

  float cE = 0.f, cO = 0.f;              // cell state for (sb, j=2sk) and (sb, j=2sk+1)
  unsigned ph = 0;
  int cur = 0;

  // ================= encoder =================
  for (int s = 0; s < Tn; ++s) {
    { // stage x_t -> A[:, 0:128]
      const float* src = ts + (size_t)(b0 + sb) * (Tn * Fn) + (size_t)s * Fn + sk * 8;
      float4 x0 = *(const float4*)src;
      float4 x1 = *(const float4*)(src + 4);
      __align__(16) unsigned short t8[8];
      t8[0] = f2bf_u16(x0.x); t8[1] = f2bf_u16(x0.y); t8[2] = f2bf_u16(x0.z); t8[3] = f2bf_u16(x0.w);
      t8[4] = f2bf_u16(x1.x); t8[5] = f2bf_u16(x1.y); t8[6] = f2bf_u16(x1.z); t8[7] = f2bf_u16(x1.w);
      *(uint4*)&A_lds[sb * 648 + sk * 8] = *(uint4*)t8;
    }
    { // stage h -> A[:, 128:640] via sc1 (L3-coherent) loads
      const unsigned long long* src = (const unsigned long long*)
          (Hg + (size_t)cur * (Bn * Hn) + (size_t)(b0 + sb) * Hn + sk * 32);
      unsigned long long v[8];
#pragma unroll
      for (int i = 0; i < 8; ++i)
        v[i] = __hip_atomic_load(src + i, __ATOMIC_RELAXED, __HIP_MEMORY_SCOPE_AGENT);
      uint4* dst = (uint4*)&A_lds[sb * 648 + 128 + sk * 32];
#pragma unroll
      for (int i = 0; i < 4; ++i) {
        uint4 t; t.x = (unsigned)v[2 * i];     t.y = (unsigned)(v[2 * i] >> 32);
                 t.z = (unsigned)v[2 * i + 1]; t.w = (unsigned)(v[2 * i + 1] >> 32);
        dst[i] = t;
      }
    }
    __syncthreads();

    floatx4 acc0 = {0.f, 0.f, 0.f, 0.f}, acc1 = {0.f, 0.f, 0.f, 0.f};
    const unsigned short* Ar = &A_lds[(rh * 16 + l15) * 648 + q * 8];
#pragma unroll
    for (int k = 0; k < KIE; ++k) {
      bf16x8 a = *(const bf16x8*)(Ar + k * 32);
      acc0 = __builtin_amdgcn_mfma_f32_16x16x32_bf16(a, Bq0[k], acc0, 0, 0, 0);
      acc1 = __builtin_amdgcn_mfma_f32_16x16x32_bf16(a, Bq1[k], acc1, 0, 0, 0);
    }
#pragma unroll
    for (int r = 0; r < 4; ++r) {
      gates_lds[g_][rh * 16 + q * 4 + r][l15] = acc0[r];
      gates_lds[g_][rh * 16 + q * 4 + r][16 + l15] = acc1[r];
    }
    __syncthreads();

    { // epilogue: thread -> (b=sb, j pair = 2sk, 2sk+1)
      float2 gi = *(const float2*)&gates_lds[0][sb][sk * 2];
      float2 gf = *(const float2*)&gates_lds[1][sb][sk * 2];
      float2 gg = *(const float2*)&gates_lds[2][sb][sk * 2];
      float2 go = *(const float2*)&gates_lds[3][sb][sk * 2];
      float2 bi = *(const float2*)&bias_lds[0][sk * 2];
      float2 bf = *(const float2*)&bias_lds[1][sk * 2];
      float2 bg = *(const float2*)&bias_lds[2][sk * 2];
      float2 bb = *(const float2*)&bias_lds[3][sk * 2];
      cE = sigm(gf.x + bf.x) * cE + sigm(gi.x + bi.x) * tanhf(gg.x + bg.x);
      cO = sigm(gf.y + bf.y) * cO + sigm(gi.y + bi.y) * tanhf(gg.y + bg.y);
      float hE = sigm(go.x + bb.x) * tanhf(cE);
      float hO = sigm(go.y + bb.y) * tanhf(cO);
      unsigned hv = (unsigned)f2bf_u16(hE) | ((unsigned)f2bf_u16(hO) << 16);
      __hip_atomic_store((unsigned*)(Hg + (size_t)(cur ^ 1) * (Bn * Hn)
                         + (size_t)(b0 + sb) * Hn + j0 + sk * 2),
                         hv, __ATOMIC_RELAXED, __HIP_MEMORY_SCOPE_AGENT);
    }
    ++ph;
    gbar(bar, wg, ph);
    cur ^= 1;
  }

  // ================= decoder =================
  bf16x8 Bd0[KID], Bd1[KID];
  {
    const bf16x8* p = (const bf16x8*)Bpd + (size_t)nt0 * (KID * 64) + l;
#pragma unroll
    for (int k = 0; k < KID; ++k) { Bd0[k] = p[k * 64]; Bd1[k] = p[(KID + k) * 64]; }
  }
  if (tid < 128) bias_lds[tid >> 5][tid & 31] = bdec[(tid >> 5) * Hn + j0 + (tid & 31)];
  const bool do_y = (ns < 8) && (g_ == 0);
  float bof = 0.f;
  if (do_y) bof = bo[ns * 16 + l15];
  if (ns < 8) { // stage this wg's 16-col Wo slice into LDS (16 KB)
    const uint4* src = (const uint4*)(Bpw + (size_t)ns * (KID * 64 * 8));
    uint4* dst = (uint4*)Bw_lds;
    dst[tid * 2] = src[tid * 2];
    dst[tid * 2 + 1] = src[tid * 2 + 1];
  }
  cE = cO = 0.f;   // reference restarts c at zero for the decoder

  for (int s = 0; s < Tn; ++s) {
    { // stage h -> A[:, 0:512]
      const unsigned long long* src = (const unsigned long long*)
          (Hg + (size_t)cur * (Bn * Hn) + (size_t)(b0 + sb) * Hn + sk * 32);
      unsigned long long v[8];
#pragma unroll
      for (int i = 0; i < 8; ++i)
        v[i] = __hip_atomic_load(src + i, __ATOMIC_RELAXED, __HIP_MEMORY_SCOPE_AGENT);
      uint4* dst = (uint4*)&A_lds[sb * 648 + sk * 32];
#pragma unroll
      for (int i = 0; i < 4; ++i) {
        uint4 t; t.x = (unsigned)v[2 * i];     t.y = (unsigned)(v[2 * i] >> 32);
                 t.z = (unsigned)v[2 * i + 1]; t.w = (unsigned)(v[2 * i + 1] >> 32);
        dst[i] = t;
      }
    }
    __syncthreads();

    floatx4 acc0 = {0.f, 0.f, 0.f, 0.f}, acc1 = {0.f, 0.f, 0.f, 0.f};
    floatx4 accy = {0.f, 0.f, 0.f, 0.f};
    const unsigned short* Ar = &A_lds[(rh * 16 + l15) * 648 + q * 8];
#pragma unroll
    for (int k = 0; k < KID; ++k) {
      bf16x8 a = *(const bf16x8*)(Ar + k * 32);
      acc0 = __builtin_amdgcn_mfma_f32_16x16x32_bf16(a, Bd0[k], acc0, 0, 0, 0);
      acc1 = __builtin_amdgcn_mfma_f32_16x16x32_bf16(a, Bd1[k], acc1, 0, 0, 0);
      if (do_y) {
        bf16x8 bw = *(const bf16x8*)&Bw_lds[(k * 64 + l) * 8];
        accy = __builtin_amdgcn_mfma_f32_16x16x32_bf16(a, bw, accy, 0, 0, 0);
      }
    }
#pragma unroll
    for (int r = 0; r < 4; ++r) {
      gates_lds[g_][rh * 16 + q * 4 + r][l15] = acc0[r];
      gates_lds[g_][rh * 16 + q * 4 + r][16 + l15] = acc1[r];
    }
    if (do_y) { // y = h@Wo.T + bo, emitted at flipped time index (pre-update h)
      size_t obase = (size_t)(b0 + rh * 16 + q * 4) * (Tn * Fn)
                   + (size_t)(Tn - 1 - s) * Fn + ns * 16 + l15;
#pragma unroll
      for (int r = 0; r < 4; ++r)
        out[obase + (size_t)r * (Tn * Fn)] = accy[r] + bof;
    }
    __syncthreads();

    { // epilogue
      float2 gi = *(const float2*)&gates_lds[0][sb][sk * 2];
      float2 gf = *(const float2*)&gates_lds[1][sb][sk * 2];
      float2 gg = *(const float2*)&gates_lds[2][sb][sk * 2];
      float2 go = *(const float2*)&gates_lds[3][sb][sk * 2];
      float2 bi = *(const float2*)&bias_lds[0][sk * 2];
      float2 bf = *(const float2*)&bias_lds[1][sk * 2];
      float2 bg = *(const float2*)&bias_lds[2][sk * 2];
      float2 bb = *(const float2*)&bias_lds[3][sk * 2];
      cE = sigm(gf.x + bf.x) * cE + sigm(gi.x + bi.x) * tanhf(gg.x + bg.x);
      cO = sigm(gf.y + bf.y) * cO + sigm(gi.y + bi.y) * tanhf(gg.y + bg.y);
      float hE = sigm(go.x + bb.x) * tanhf(cE);
      float hO = sigm(go.y + bb.y) * tanhf(cO);
      unsigned hv = (unsigned)f2bf_u16(hE) | ((unsigned)f2bf_u16(hO) << 16);
      __hip_atomic_store((unsigned*)(Hg + (size_t)(cur ^ 1) * (Bn * Hn)
                         + (size_t)(b0 + sb) * Hn + j0 + sk * 2),
                         hv, __ATOMIC_RELAXED, __HIP_MEMORY_SCOPE_AGENT);
    }
    ++ph;
    gbar(bar, wg, ph);
    cur ^= 1;
  }
}

extern "C" void kernel_launch(void* const* d_in, const int* in_sizes, int n_in,
                              void* d_out, int out_size, void* d_ws, size_t ws_size,
                              hipStream_t stream) {
  const float* ts   = (const float*)d_in[0];
  const float* eWih = (const float*)d_in[1];
  const float* eWhh = (const float*)d_in[2];
  const float* ebih = (const float*)d_in[3];
  const float* ebhh = (const float*)d_in[4];
  const float* dWih = (const float*)d_in[5];
  const float* dWhh = (const float*)d_in[6];
  const float* dbih = (const float*)d_in[7];
  const float* dbhh = (const float*)d_in[8];
  const float* Wo   = (const float*)d_in[9];
  const float* bo   = (const float*)d_in[10];
  float* outp = (float*)d_out;

  char* ws = (char*)d_ws;
  unsigned short* Bpe  = (unsigned short*)(ws);                 // 2,621,440 B
  unsigned short* Bpd  = (unsigned short*)(ws + 2621440);       // 2,097,152 B
  unsigned short* Bpw  = (unsigned short*)(ws + 4718592);       //   131,072 B
  float*          benc = (float*)(ws + 4849664);                //     8,192 B
  float*          bdec = (float*)(ws + 4857856);                //     8,192 B
  unsigned short* Hg   = (unsigned short*)(ws + 4866048);       // 1,048,576 B
  unsigned*       bar  = (unsigned*)(ws + 5914624);             //     2,048 B

  pack_enc_k<<<128 * KIE, 64, 0, stream>>>(eWih, eWhh, Bpe);
  pack_dec_k<<<128 * KID, 64, 0, stream>>>(dWih, dWhh, Wo, Bpd);
  pack_wo_k<<<8 * KID, 64, 0, stream>>>(Wo, Bpw);
  bias_k<<<8, 256, 0, stream>>>(ebih, ebhh, dbih, dbhh, dWih, bo, benc, bdec);
  init_k<<<256, 256, 0, stream>>>((unsigned long long*)Hg, bar);

  lstm_persist<<<NWG, 512, 0, stream>>>(ts, Bpe, Bpd, Bpw, benc, bdec, bo, Hg, bar, outp);
}

// Round 3
// 2449.659 us; speedup vs baseline: 7.2512x; 1.4604x over previous
//
#include <hip/hip_runtime.h>

#define Bn 512
#define Tn 256
#define Fn 128
#define Hn 512
#define KIE 20   // 640/32 k-iters (encoder: [x|h], K=640)
#define KID 16   // 512/32 k-iters (decoder: h only, K=512)
#define NWG 256

typedef __attribute__((ext_vector_type(8))) __bf16 bf16x8;
typedef __attribute__((ext_vector_type(4))) float floatx4;

__device__ __forceinline__ unsigned short f2bf_u16(float f) {
  union { float f; unsigned u; } v; v.f = f;
  unsigned r = v.u + 0x7FFFu + ((v.u >> 16) & 1u);   // RNE
  return (unsigned short)(r >> 16);
}

// fast sigmoid/tanh via v_exp_f32 + v_rcp_f32 (error ~1e-6, << bf16 rounding)
__device__ __forceinline__ float sigm(float x) {
  return __builtin_amdgcn_rcpf(1.f + __expf(-x));
}
__device__ __forceinline__ float ftanh(float x) {
  return 1.f - 2.f * __builtin_amdgcn_rcpf(1.f + __expf(2.f * x));
}

// ---- pack encoder weights [x|h] -> B-fragment order [nt][ki][lane][8] ----
__global__ void pack_enc_k(const float* __restrict__ Wih, const float* __restrict__ Whh,
                           unsigned short* __restrict__ Bpe) {
  int id = blockIdx.x;              // nt*KIE + ki
  int nt = id / KIE, ki = id % KIE;
  int l = threadIdx.x;
  int n = nt * 16 + (l & 15);
  int kb = ki * 32 + (l >> 4) * 8;
  __align__(16) unsigned short o[8];
#pragma unroll
  for (int j = 0; j < 8; ++j) {
    int k = kb + j;
    float v = (k < Fn) ? Wih[n * Fn + k] : Whh[n * Hn + (k - Fn)];
    o[j] = f2bf_u16(v);
  }
  *(uint4*)(Bpe + (size_t)(id * 64 + l) * 8) = *(uint4*)o;
}

// ---- pack decoder combined weights (W_hh + W_ih@Wo) -> fragment order ----
__global__ void pack_dec_k(const float* __restrict__ Wih, const float* __restrict__ Whh,
                           const float* __restrict__ Wo, unsigned short* __restrict__ Bpd) {
  int id = blockIdx.x;              // nt*KID + ki
  int nt = id / KID, ki = id % KID;
  int l = threadIdx.x;
  int n = nt * 16 + (l & 15);
  int kb = ki * 32 + (l >> 4) * 8;
  float acc[8];
#pragma unroll
  for (int j = 0; j < 8; ++j) acc[j] = Whh[n * Hn + kb + j];
  for (int f = 0; f < Fn; ++f) {
    float wf = Wih[n * Fn + f];
    const float* wo = Wo + f * Hn + kb;
#pragma unroll
    for (int j = 0; j < 8; ++j) acc[j] += wf * wo[j];
  }
  __align__(16) unsigned short o[8];
#pragma unroll
  for (int j = 0; j < 8; ++j) o[j] = f2bf_u16(acc[j]);
  *(uint4*)(Bpd + (size_t)(id * 64 + l) * 8) = *(uint4*)o;
}

// ---- pack Wo (for y = h@Wo.T) -> fragment order [ft][ki][lane][8] ----
__global__ void pack_wo_k(const float* __restrict__ Wo, unsigned short* __restrict__ Bpw) {
  int id = blockIdx.x;              // ft*KID + ki
  int ft = id / KID, ki = id % KID;
  int l = threadIdx.x;
  int f = ft * 16 + (l & 15);
  int kb = ki * 32 + (l >> 4) * 8;
  __align__(16) unsigned short o[8];
#pragma unroll
  for (int j = 0; j < 8; ++j) o[j] = f2bf_u16(Wo[f * Hn + kb + j]);
  *(uint4*)(Bpw + (size_t)(id * 64 + l) * 8) = *(uint4*)o;
}

// ---- biases: benc = eb_ih+eb_hh ; bdec = db_ih+db_hh + dW_ih@bo ----
__global__ void bias_k(const float* __restrict__ ebih, const float* __restrict__ ebhh,
                       const float* __restrict__ dbih, const float* __restrict__ dbhh,
                       const float* __restrict__ dWih, const float* __restrict__ bo,
                       float* __restrict__ benc, float* __restrict__ bdec) {
  int n = blockIdx.x * blockDim.x + threadIdx.x;  // 2048
  benc[n] = ebih[n] + ebhh[n];
  float a = dbih[n] + dbhh[n];
  for (int f = 0; f < Fn; ++f) a += dWih[n * Fn + f] * bo[f];
  bdec[n] = a;
}

// ---- pack x: ts[b][s][k] fp32 -> xp[s][b][k] bf16 ----
__global__ void pack_x_k(const float* __restrict__ ts, unsigned short* __restrict__ xp) {
  size_t i = (size_t)blockIdx.x * 256 + threadIdx.x;   // quad index, 512*256*32
  int k4 = (int)(i & 31);
  size_t bs = i >> 5;
  int s = (int)(bs & 255);
  size_t b = bs >> 8;
  float4 v = *(const float4*)(ts + (i << 2));
  __align__(8) unsigned short o[4];
  o[0] = f2bf_u16(v.x); o[1] = f2bf_u16(v.y); o[2] = f2bf_u16(v.z); o[3] = f2bf_u16(v.w);
  *(unsigned long long*)(xp + ((size_t)s * Bn + b) * Fn + k4 * 4) = *(unsigned long long*)o;
}

// ---- init: zero Hg buffer 0 (512 KB) + flags (32 KB) ----
__global__ void init_k(unsigned long long* __restrict__ Hg0, unsigned* __restrict__ flg) {
  int i = blockIdx.x * 256 + threadIdx.x;   // 65536
  Hg0[i] = 0ULL;
  if (i < 8192) flg[i] = 0u;
}

// ---- persistent LSTM encoder-decoder: 256 wgs x 512 thr, group flag barrier ----
__global__ __launch_bounds__(512, 2) void lstm_persist(
    const unsigned short* __restrict__ xp,
    const unsigned short* __restrict__ Bpe,
    const unsigned short* __restrict__ Bpd,
    const unsigned short* __restrict__ Bpw,
    const float* __restrict__ benc,
    const float* __restrict__ bdec,
    const float* __restrict__ bo,
    unsigned short* __restrict__ Hg,   // [2][512][512] bf16 double buffer (sc1 only)
    unsigned* __restrict__ flg,        // 256 lines x 128 B, monotone phase per wg
    float* __restrict__ out)           // [512][256][128] fp32
{
  const int wg = blockIdx.x;
  const int mg = wg >> 4, ns = wg & 15;
  const int b0 = mg * 32, j0 = ns * 32;
  const int tid = threadIdx.x;
  const int w = tid >> 6, l = tid & 63;
  const int l15 = l & 15, q = l >> 4;
  const int g_ = w >> 1, rh = w & 1;     // wave = (gate, row-half)
  const int sb = tid >> 4, sk = tid & 15;

  __shared__ __align__(16) unsigned short A_lds[32 * 648];       // 32 rows x 640 (+8 pad)
  __shared__ __align__(16) float gates_lds[4][32][34];
  __shared__ __align__(16) unsigned short Bw_lds[KID * 64 * 8];  // 16 KB Wo slice

  const int nt0 = g_ * 32 + ns * 2;

  // ---- preload encoder B tiles into registers ----
  bf16x8 Bq0[KIE], Bq1[KIE];
  {
    const bf16x8* p = (const bf16x8*)Bpe + (size_t)nt0 * (KIE * 64) + l;
#pragma unroll
    for (int k = 0; k < KIE; ++k) { Bq0[k] = p[k * 64]; Bq1[k] = p[(KIE + k) * 64]; }
  }
  // per-thread gate biases (encoder) in registers
  float2 bi = *(const float2*)(benc + 0 * Hn + j0 + sk * 2);
  float2 bf = *(const float2*)(benc + 1 * Hn + j0 + sk * 2);
  float2 bg = *(const float2*)(benc + 2 * Hn + j0 + sk * 2);
  float2 bb = *(const float2*)(benc + 3 * Hn + j0 + sk * 2);

  if (ns < 8) { // constant Wo slice -> LDS, once
    const uint4* src = (const uint4*)(Bpw + (size_t)ns * (KID * 64 * 8));
    uint4* dst = (uint4*)Bw_lds;
    dst[tid * 2] = src[tid * 2];
    dst[tid * 2 + 1] = src[tid * 2 + 1];
  }
  { // pre-stage x_0
    uint4 xv = *(const uint4*)(xp + ((size_t)(b0 + sb)) * Fn + sk * 8);
    *(uint4*)&A_lds[sb * 648 + sk * 8] = xv;
  }

  float cE = 0.f, cO = 0.f;
  unsigned ph = 0;
  int cur = 0;

  // ================= encoder =================
  for (int s = 0; s < Tn; ++s) {
    // wait for this group's 16 producers to reach phase ph
    if (l < 16) {
      const unsigned* fp = flg + (size_t)(mg * 16 + l) * 32;
      while (__hip_atomic_load(fp, __ATOMIC_RELAXED, __HIP_MEMORY_SCOPE_AGENT) < ph)
        __builtin_amdgcn_s_sleep(1);
    }
    __asm__ __volatile__("" ::: "memory");

    { // stage h -> A[:, 128:640] via sc1 (L3-coherent) loads
      const unsigned long long* src = (const unsigned long long*)
          (Hg + (size_t)cur * (Bn * Hn) + (size_t)(b0 + sb) * Hn + sk * 32);
      unsigned long long v[8];
#pragma unroll
      for (int i = 0; i < 8; ++i)
        v[i] = __hip_atomic_load(src + i, __ATOMIC_RELAXED, __HIP_MEMORY_SCOPE_AGENT);
      uint4* dst = (uint4*)&A_lds[sb * 648 + 128 + sk * 32];
#pragma unroll
      for (int i = 0; i < 4; ++i) {
        uint4 t; t.x = (unsigned)v[2 * i];     t.y = (unsigned)(v[2 * i] >> 32);
                 t.z = (unsigned)v[2 * i + 1]; t.w = (unsigned)(v[2 * i + 1] >> 32);
        dst[i] = t;
      }
    }
    __syncthreads();   // sync1: A ready

    floatx4 acc0 = {0.f, 0.f, 0.f, 0.f}, acc1 = {0.f, 0.f, 0.f, 0.f};
    const unsigned short* Ar = &A_lds[(rh * 16 + l15) * 648 + q * 8];
#pragma unroll
    for (int k = 0; k < KIE; ++k) {
      bf16x8 a = *(const bf16x8*)(Ar + k * 32);
      acc0 = __builtin_amdgcn_mfma_f32_16x16x32_bf16(a, Bq0[k], acc0, 0, 0, 0);
      acc1 = __builtin_amdgcn_mfma_f32_16x16x32_bf16(a, Bq1[k], acc1, 0, 0, 0);
    }
#pragma unroll
    for (int r = 0; r < 4; ++r) {
      gates_lds[g_][rh * 16 + q * 4 + r][l15] = acc0[r];
      gates_lds[g_][rh * 16 + q * 4 + r][16 + l15] = acc1[r];
    }
    __syncthreads();   // sync2: gates ready, A free

    // prefetch next x (hides L3/L2 latency under epilogue)
    int sn = (s + 1 < Tn) ? s + 1 : Tn - 1;
    uint4 xv = *(const uint4*)(xp + ((size_t)sn * Bn + (b0 + sb)) * Fn + sk * 8);

    { // epilogue: thread -> (b=sb, j pair = 2sk, 2sk+1)
      float2 gi2 = *(const float2*)&gates_lds[0][sb][sk * 2];
      float2 gf2 = *(const float2*)&gates_lds[1][sb][sk * 2];
      float2 gg2 = *(const float2*)&gates_lds[2][sb][sk * 2];
      float2 go2 = *(const float2*)&gates_lds[3][sb][sk * 2];
      cE = sigm(gf2.x + bf.x) * cE + sigm(gi2.x + bi.x) * ftanh(gg2.x + bg.x);
      cO = sigm(gf2.y + bf.y) * cO + sigm(gi2.y + bi.y) * ftanh(gg2.y + bg.y);
      float hE = sigm(go2.x + bb.x) * ftanh(cE);
      float hO = sigm(go2.y + bb.y) * ftanh(cO);
      unsigned hv = (unsigned)f2bf_u16(hE) | ((unsigned)f2bf_u16(hO) << 16);
      __hip_atomic_store((unsigned*)(Hg + (size_t)(cur ^ 1) * (Bn * Hn)
                         + (size_t)(b0 + sb) * Hn + j0 + sk * 2),
                         hv, __ATOMIC_RELAXED, __HIP_MEMORY_SCOPE_AGENT);
    }
    // write prefetched x for step s+1 (A free since sync2)
    *(uint4*)&A_lds[sb * 648 + sk * 8] = xv;

    __syncthreads();   // sync3: h stores drained (vmcnt) by all waves
    if (tid == 0)
      __hip_atomic_store(flg + (size_t)wg * 32, ph + 1,
                         __ATOMIC_RELAXED, __HIP_MEMORY_SCOPE_AGENT);
    ++ph;
    cur ^= 1;
  }

  // ================= decoder =================
  bf16x8 Bd0[KID], Bd1[KID];
  {
    const bf16x8* p = (const bf16x8*)Bpd + (size_t)nt0 * (KID * 64) + l;
#pragma unroll
    for (int k = 0; k < KID; ++k) { Bd0[k] = p[k * 64]; Bd1[k] = p[(KID + k) * 64]; }
  }
  bi = *(const float2*)(bdec + 0 * Hn + j0 + sk * 2);
  bf = *(const float2*)(bdec + 1 * Hn + j0 + sk * 2);
  bg = *(const float2*)(bdec + 2 * Hn + j0 + sk * 2);
  bb = *(const float2*)(bdec + 3 * Hn + j0 + sk * 2);
  const bool do_y = (ns < 8) && (g_ == 0);
  float bof = 0.f;
  if (do_y) bof = bo[ns * 16 + l15];
  cE = cO = 0.f;   // reference restarts c at zero for the decoder

  for (int s = 0; s < Tn; ++s) {
    if (l < 16) {
      const unsigned* fp = flg + (size_t)(mg * 16 + l) * 32;
      while (__hip_atomic_load(fp, __ATOMIC_RELAXED, __HIP_MEMORY_SCOPE_AGENT) < ph)
        __builtin_amdgcn_s_sleep(1);
    }
    __asm__ __volatile__("" ::: "memory");

    { // stage h -> A[:, 0:512]
      const unsigned long long* src = (const unsigned long long*)
          (Hg + (size_t)cur * (Bn * Hn) + (size_t)(b0 + sb) * Hn + sk * 32);
      unsigned long long v[8];
#pragma unroll
      for (int i = 0; i < 8; ++i)
        v[i] = __hip_atomic_load(src + i, __ATOMIC_RELAXED, __HIP_MEMORY_SCOPE_AGENT);
      uint4* dst = (uint4*)&A_lds[sb * 648 + sk * 32];
#pragma unroll
      for (int i = 0; i < 4; ++i) {
        uint4 t; t.x = (unsigned)v[2 * i];     t.y = (unsigned)(v[2 * i] >> 32);
                 t.z = (unsigned)v[2 * i + 1]; t.w = (unsigned)(v[2 * i + 1] >> 32);
        dst[i] = t;
      }
    }
    __syncthreads();   // sync1

    floatx4 acc0 = {0.f, 0.f, 0.f, 0.f}, acc1 = {0.f, 0.f, 0.f, 0.f};
    floatx4 accy = {0.f, 0.f, 0.f, 0.f};
    const unsigned short* Ar = &A_lds[(rh * 16 + l15) * 648 + q * 8];
#pragma unroll
    for (int k = 0; k < KID; ++k) {
      bf16x8 a = *(const bf16x8*)(Ar + k * 32);
      acc0 = __builtin_amdgcn_mfma_f32_16x16x32_bf16(a, Bd0[k], acc0, 0, 0, 0);
      acc1 = __builtin_amdgcn_mfma_f32_16x16x32_bf16(a, Bd1[k], acc1, 0, 0, 0);
      if (do_y) {
        bf16x8 bw = *(const bf16x8*)&Bw_lds[(k * 64 + l) * 8];
        accy = __builtin_amdgcn_mfma_f32_16x16x32_bf16(a, bw, accy, 0, 0, 0);
      }
    }
#pragma unroll
    for (int r = 0; r < 4; ++r) {
      gates_lds[g_][rh * 16 + q * 4 + r][l15] = acc0[r];
      gates_lds[g_][rh * 16 + q * 4 + r][16 + l15] = acc1[r];
    }
    if (do_y) { // y = h@Wo.T + bo, emitted at flipped time index (pre-update h)
      size_t obase = (size_t)(b0 + rh * 16 + q * 4) * (Tn * Fn)
                   + (size_t)(Tn - 1 - s) * Fn + ns * 16 + l15;
#pragma unroll
      for (int r = 0; r < 4; ++r)
        out[obase + (size_t)r * (Tn * Fn)] = accy[r] + bof;
    }
    __syncthreads();   // sync2

    { // epilogue
      float2 gi2 = *(const float2*)&gates_lds[0][sb][sk * 2];
      float2 gf2 = *(const float2*)&gates_lds[1][sb][sk * 2];
      float2 gg2 = *(const float2*)&gates_lds[2][sb][sk * 2];
      float2 go2 = *(const float2*)&gates_lds[3][sb][sk * 2];
      cE = sigm(gf2.x + bf.x) * cE + sigm(gi2.x + bi.x) * ftanh(gg2.x + bg.x);
      cO = sigm(gf2.y + bf.y) * cO + sigm(gi2.y + bi.y) * ftanh(gg2.y + bg.y);
      float hE = sigm(go2.x + bb.x) * ftanh(cE);
      float hO = sigm(go2.y + bb.y) * ftanh(cO);
      unsigned hv = (unsigned)f2bf_u16(hE) | ((unsigned)f2bf_u16(hO) << 16);
      __hip_atomic_store((unsigned*)(Hg + (size_t)(cur ^ 1) * (Bn * Hn)
                         + (size_t)(b0 + sb) * Hn + j0 + sk * 2),
                         hv, __ATOMIC_RELAXED, __HIP_MEMORY_SCOPE_AGENT);
    }
    __syncthreads();   // sync3: h stores drained
    if (tid == 0)
      __hip_atomic_store(flg + (size_t)wg * 32, ph + 1,
                         __ATOMIC_RELAXED, __HIP_MEMORY_SCOPE_AGENT);
    ++ph;
    cur ^= 1;
  }
}

extern "C" void kernel_launch(void* const* d_in, const int* in_sizes, int n_in,
                              void* d_out, int out_size, void* d_ws, size_t ws_size,
                              hipStream_t stream) {
  const float* ts   = (const float*)d_in[0];
  const float* eWih = (const float*)d_in[1];
  const float* eWhh = (const float*)d_in[2];
  const float* ebih = (const float*)d_in[3];
  const float* ebhh = (const float*)d_in[4];
  const float* dWih = (const float*)d_in[5];
  const float* dWhh = (const float*)d_in[6];
  const float* dbih = (const float*)d_in[7];
  const float* dbhh = (const float*)d_in[8];
  const float* Wo   = (const float*)d_in[9];
  const float* bo   = (const float*)d_in[10];
  float* outp = (float*)d_out;

  char* ws = (char*)d_ws;
  unsigned short* Bpe  = (unsigned short*)(ws);                 // 2,621,440 B
  unsigned short* Bpd  = (unsigned short*)(ws + 2621440);       // 2,097,152 B
  unsigned short* Bpw  = (unsigned short*)(ws + 4718592);       //   131,072 B
  float*          benc = (float*)(ws + 4849664);                //     8,192 B
  float*          bdec = (float*)(ws + 4857856);                //     8,192 B
  unsigned short* Hg   = (unsigned short*)(ws + 4866048);       // 1,048,576 B
  unsigned*       flg  = (unsigned*)(ws + 5914624);             //    32,768 B
  unsigned short* xp   = (unsigned short*)(ws + 5947392);       // 16,777,216 B

  pack_enc_k<<<128 * KIE, 64, 0, stream>>>(eWih, eWhh, Bpe);
  pack_dec_k<<<128 * KID, 64, 0, stream>>>(dWih, dWhh, Wo, Bpd);
  pack_wo_k<<<8 * KID, 64, 0, stream>>>(Wo, Bpw);
  bias_k<<<8, 256, 0, stream>>>(ebih, ebhh, dbih, dbhh, dWih, bo, benc, bdec);
  pack_x_k<<<16384, 256, 0, stream>>>(ts, xp);
  init_k<<<256, 256, 0, stream>>>((unsigned long long*)Hg, flg);

  lstm_persist<<<NWG, 512, 0, stream>>>(xp, Bpe, Bpd, Bpw, benc, bdec, bo, Hg, flg, outp);
}

// Round 4
// 2242.394 us; speedup vs baseline: 7.9214x; 1.0924x over previous
//
#include <hip/hip_runtime.h>

#define Bn 512
#define Tn 256
#define Fn 128
#define Hn 512
#define KIE 20   // 640/32 k-iters (encoder: [x|h], K=640)
#define KID 16   // 512/32 k-iters (decoder: h only, K=512)
#define NWG 256
#define RS 648   // A_lds row stride in ushorts (16B-aligned)

typedef __attribute__((ext_vector_type(8))) __bf16 bf16x8;
typedef __attribute__((ext_vector_type(4))) float floatx4;

__device__ __forceinline__ unsigned short f2bf_u16(float f) {
  union { float f; unsigned u; } v; v.f = f;
  unsigned r = v.u + 0x7FFFu + ((v.u >> 16) & 1u);   // RNE
  return (unsigned short)(r >> 16);
}

// fast sigmoid/tanh via v_exp_f32 + v_rcp_f32 (error ~1e-6, << bf16 rounding)
__device__ __forceinline__ float sigm(float x) {
  return __builtin_amdgcn_rcpf(1.f + __expf(-x));
}
__device__ __forceinline__ float ftanh(float x) {
  return 1.f - 2.f * __builtin_amdgcn_rcpf(1.f + __expf(2.f * x));
}

// ---- pack encoder weights [x|h] -> B-fragment order [nt][ki][lane][8] ----
__global__ void pack_enc_k(const float* __restrict__ Wih, const float* __restrict__ Whh,
                           unsigned short* __restrict__ Bpe) {
  int id = blockIdx.x;              // nt*KIE + ki
  int nt = id / KIE, ki = id % KIE;
  int l = threadIdx.x;
  int n = nt * 16 + (l & 15);
  int kb = ki * 32 + (l >> 4) * 8;
  __align__(16) unsigned short o[8];
#pragma unroll
  for (int j = 0; j < 8; ++j) {
    int k = kb + j;
    float v = (k < Fn) ? Wih[n * Fn + k] : Whh[n * Hn + (k - Fn)];
    o[j] = f2bf_u16(v);
  }
  *(uint4*)(Bpe + (size_t)(id * 64 + l) * 8) = *(uint4*)o;
}

// ---- pack decoder combined weights (W_hh + W_ih@Wo) -> fragment order ----
__global__ void pack_dec_k(const float* __restrict__ Wih, const float* __restrict__ Whh,
                           const float* __restrict__ Wo, unsigned short* __restrict__ Bpd) {
  int id = blockIdx.x;              // nt*KID + ki
  int nt = id / KID, ki = id % KID;
  int l = threadIdx.x;
  int n = nt * 16 + (l & 15);
  int kb = ki * 32 + (l >> 4) * 8;
  float acc[8];
#pragma unroll
  for (int j = 0; j < 8; ++j) acc[j] = Whh[n * Hn + kb + j];
  for (int f = 0; f < Fn; ++f) {
    float wf = Wih[n * Fn + f];
    const float* wo = Wo + f * Hn + kb;
#pragma unroll
    for (int j = 0; j < 8; ++j) acc[j] += wf * wo[j];
  }
  __align__(16) unsigned short o[8];
#pragma unroll
  for (int j = 0; j < 8; ++j) o[j] = f2bf_u16(acc[j]);
  *(uint4*)(Bpd + (size_t)(id * 64 + l) * 8) = *(uint4*)o;
}

// ---- pack Wo (for y = h@Wo.T) -> fragment order [ft][ki][lane][8] ----
__global__ void pack_wo_k(const float* __restrict__ Wo, unsigned short* __restrict__ Bpw) {
  int id = blockIdx.x;              // ft*KID + ki
  int ft = id / KID, ki = id % KID;
  int l = threadIdx.x;
  int f = ft * 16 + (l & 15);
  int kb = ki * 32 + (l >> 4) * 8;
  __align__(16) unsigned short o[8];
#pragma unroll
  for (int j = 0; j < 8; ++j) o[j] = f2bf_u16(Wo[f * Hn + kb + j]);
  *(uint4*)(Bpw + (size_t)(id * 64 + l) * 8) = *(uint4*)o;
}

// ---- biases: benc = eb_ih+eb_hh ; bdec = db_ih+db_hh + dW_ih@bo ----
__global__ void bias_k(const float* __restrict__ ebih, const float* __restrict__ ebhh,
                       const float* __restrict__ dbih, const float* __restrict__ dbhh,
                       const float* __restrict__ dWih, const float* __restrict__ bo,
                       float* __restrict__ benc, float* __restrict__ bdec) {
  int n = blockIdx.x * blockDim.x + threadIdx.x;  // 2048
  benc[n] = ebih[n] + ebhh[n];
  float a = dbih[n] + dbhh[n];
  for (int f = 0; f < Fn; ++f) a += dWih[n * Fn + f] * bo[f];
  bdec[n] = a;
}

// ---- pack x: ts[b][s][k] fp32 -> xp[s][b][k] bf16 ----
__global__ void pack_x_k(const float* __restrict__ ts, unsigned short* __restrict__ xp) {
  size_t i = (size_t)blockIdx.x * 256 + threadIdx.x;   // quad index
  int k4 = (int)(i & 31);
  size_t bs = i >> 5;
  int s = (int)(bs & 255);
  size_t b = bs >> 8;
  float4 v = *(const float4*)(ts + (i << 2));
  __align__(8) unsigned short o[4];
  o[0] = f2bf_u16(v.x); o[1] = f2bf_u16(v.y); o[2] = f2bf_u16(v.z); o[3] = f2bf_u16(v.w);
  *(unsigned long long*)(xp + ((size_t)s * Bn + b) * Fn + k4 * 4) = *(unsigned long long*)o;
}

// ---- init: zero Hg buffer 0 (512 KB) + both flag arrays ----
__global__ void init_k(unsigned long long* __restrict__ Hg0,
                       unsigned* __restrict__ flgA, unsigned* __restrict__ flgB) {
  int i = blockIdx.x * 256 + threadIdx.x;   // 65536
  Hg0[i] = 0ULL;
  if (i < 8192) { flgA[i] = 0u; flgB[i] = 0u; }
}

#define POLL(F, p) do { \
  if (l < 16) { \
    const unsigned* fp_ = (F) + (size_t)(mg * 16 + l) * 32; \
    while (__hip_atomic_load(fp_, __ATOMIC_RELAXED, __HIP_MEMORY_SCOPE_AGENT) < (unsigned)(p)) \
      __builtin_amdgcn_s_sleep(1); \
  } \
  __asm__ __volatile__("" ::: "memory"); \
} while (0)

#define SETF(F, p) do { if (tid == 0) \
  __hip_atomic_store((F) + (size_t)wg * 32, (unsigned)(p), __ATOMIC_RELAXED, __HIP_MEMORY_SCOPE_AGENT); \
} while (0)

#define STAGE_H(bb, OFF, curbuf) do { \
  const unsigned long long* src_ = (const unsigned long long*) \
      (Hg + (size_t)(curbuf) * (Bn * Hn) + (size_t)((bb) + eb) * Hn + ej * 16); \
  unsigned long long v0_ = __hip_atomic_load(src_ + 0, __ATOMIC_RELAXED, __HIP_MEMORY_SCOPE_AGENT); \
  unsigned long long v1_ = __hip_atomic_load(src_ + 1, __ATOMIC_RELAXED, __HIP_MEMORY_SCOPE_AGENT); \
  unsigned long long v2_ = __hip_atomic_load(src_ + 2, __ATOMIC_RELAXED, __HIP_MEMORY_SCOPE_AGENT); \
  unsigned long long v3_ = __hip_atomic_load(src_ + 3, __ATOMIC_RELAXED, __HIP_MEMORY_SCOPE_AGENT); \
  uint4* dst_ = (uint4*)&A_lds[eb * RS + (OFF) + ej * 16]; \
  uint4 t0_, t1_; \
  t0_.x = (unsigned)v0_; t0_.y = (unsigned)(v0_ >> 32); t0_.z = (unsigned)v1_; t0_.w = (unsigned)(v1_ >> 32); \
  t1_.x = (unsigned)v2_; t1_.y = (unsigned)(v2_ >> 32); t1_.z = (unsigned)v3_; t1_.w = (unsigned)(v3_ >> 32); \
  dst_[0] = t0_; dst_[1] = t1_; \
} while (0)

#define STAGE_X(bb, s_) do { if (tid < 256) { \
  uint4 xv_ = *(const uint4*)(xp + ((size_t)(s_) * Bn + (bb) + (tid >> 4)) * Fn + (tid & 15) * 8); \
  *(uint4*)&A_lds[(tid >> 4) * RS + (tid & 15) * 8] = xv_; \
} } while (0)

#define MFMA_GATES(BR, KN) do { \
  floatx4 acc_ = {0.f, 0.f, 0.f, 0.f}; \
  const unsigned short* Ar_ = &A_lds[l15 * RS + q * 8]; \
  _Pragma("unroll") for (int k = 0; k < (KN); ++k) \
    acc_ = __builtin_amdgcn_mfma_f32_16x16x32_bf16(*(const bf16x8*)(Ar_ + k * 32), (BR)[k], acc_, 0, 0, 0); \
  _Pragma("unroll") for (int r = 0; r < 4; ++r) \
    gates_lds[g_][q * 4 + r][nsub * 16 + l15] = acc_[r]; \
} while (0)

#define MFMA_GATES_Y(BR, doY, bb, sd) do { \
  floatx4 acc_ = {0.f, 0.f, 0.f, 0.f}, accy_ = {0.f, 0.f, 0.f, 0.f}; \
  const unsigned short* Ar_ = &A_lds[l15 * RS + q * 8]; \
  _Pragma("unroll") for (int k = 0; k < KID; ++k) { \
    bf16x8 a_ = *(const bf16x8*)(Ar_ + k * 32); \
    acc_ = __builtin_amdgcn_mfma_f32_16x16x32_bf16(a_, (BR)[k], acc_, 0, 0, 0); \
    if (doY) accy_ = __builtin_amdgcn_mfma_f32_16x16x32_bf16( \
        a_, *(const bf16x8*)&Bw_lds[(k * 64 + l) * 8], accy_, 0, 0, 0); \
  } \
  _Pragma("unroll") for (int r = 0; r < 4; ++r) \
    gates_lds[g_][q * 4 + r][nsub * 16 + l15] = acc_[r]; \
  if (doY) { \
    _Pragma("unroll") for (int r = 0; r < 4; ++r) \
      __builtin_nontemporal_store(accy_[r] + bof, \
        out + ((size_t)((bb) + q * 4 + r) * Tn + (Tn - 1 - (sd))) * Fn + ns * 16 + l15); \
  } \
} while (0)

#define EPI(cvar, BI, BF, BG, BO, bb, nxtbuf) do { \
  float gi_ = gates_lds[0][eb][ej] + (BI); \
  float gf_ = gates_lds[1][eb][ej] + (BF); \
  float gg_ = gates_lds[2][eb][ej] + (BG); \
  float go_ = gates_lds[3][eb][ej] + (BO); \
  cvar = sigm(gf_) * cvar + sigm(gi_) * ftanh(gg_); \
  float h_ = sigm(go_) * ftanh(cvar); \
  __hip_atomic_store(Hg + (size_t)(nxtbuf) * (Bn * Hn) + (size_t)((bb) + eb) * Hn + j0 + ej, \
      (unsigned short)f2bf_u16(h_), __ATOMIC_RELAXED, __HIP_MEMORY_SCOPE_AGENT); \
} while (0)

// ---- persistent LSTM enc-dec: 256 wgs x 512 thr, two 16-row streams/wg ----
__global__ __launch_bounds__(512, 2) void lstm_persist(
    const unsigned short* __restrict__ xp,
    const unsigned short* __restrict__ Bpe,
    const unsigned short* __restrict__ Bpd,
    const unsigned short* __restrict__ Bpw,
    const float* __restrict__ benc,
    const float* __restrict__ bdec,
    const float* __restrict__ bo,
    unsigned short* __restrict__ Hg,   // [2][512][512] bf16 (sc1 access only)
    unsigned* __restrict__ flgA,
    unsigned* __restrict__ flgB,
    float* __restrict__ out)           // [512][256][128] fp32
{
  const int wg = blockIdx.x;
  const int mg = wg >> 4, ns = wg & 15;
  const int b0 = mg * 32, j0 = ns * 32;
  const int tid = threadIdx.x;
  const int w = tid >> 6, l = tid & 63;
  const int l15 = l & 15, q = l >> 4;
  const int g_ = w >> 1, nsub = w & 1;       // wave = (gate, 16-col subtile)
  const int nt = g_ * 32 + ns * 2 + nsub;
  const int eb = tid >> 5, ej = tid & 31;    // epilogue/staging (row, col)

  __shared__ __align__(16) unsigned short A_lds[16 * RS];        // 20.7 KB
  __shared__ __align__(16) float gates_lds[4][16][34];           //  8.7 KB
  __shared__ __align__(16) unsigned short Bw_lds[KID * 64 * 8];  // 16.4 KB

  // ---- preload B tiles (enc + dec) into registers: (20+16)*4 = 144 VGPRs ----
  bf16x8 Bq[KIE], Bd[KID];
  {
    const bf16x8* p = (const bf16x8*)Bpe + (size_t)nt * (KIE * 64) + l;
#pragma unroll
    for (int k = 0; k < KIE; ++k) Bq[k] = p[k * 64];
  }
  {
    const bf16x8* p = (const bf16x8*)Bpd + (size_t)nt * (KID * 64) + l;
#pragma unroll
    for (int k = 0; k < KID; ++k) Bd[k] = p[k * 64];
  }
  // per-thread gate biases
  const float bie = benc[0 * Hn + j0 + ej], bfe = benc[1 * Hn + j0 + ej];
  const float bge = benc[2 * Hn + j0 + ej], boe = benc[3 * Hn + j0 + ej];
  const float bid = bdec[0 * Hn + j0 + ej], bfd = bdec[1 * Hn + j0 + ej];
  const float bgd = bdec[2 * Hn + j0 + ej], bod = bdec[3 * Hn + j0 + ej];

  if (ns < 8) { // constant Wo slice -> LDS, once
    const uint4* src = (const uint4*)(Bpw + (size_t)ns * (KID * 64 * 8));
    uint4* dst = (uint4*)Bw_lds;
    dst[tid * 2] = src[tid * 2];
    dst[tid * 2 + 1] = src[tid * 2 + 1];
  }
  const bool yA = (ns < 8) && (w == 0);
  const bool yB = (ns < 8) && (w == 4);
  float bof = 0.f;
  if (yA || yB) bof = bo[ns * 16 + l15];

  const int bbA = b0, bbB = b0 + 16;
  float cA = 0.f, cB = 0.f;

  // ================= encoder =================
  for (int s = 0; s < Tn; ++s) {
    const int cur = s & 1, nxt = cur ^ 1;
    POLL(flgA, s);
    STAGE_X(bbA, s);
    STAGE_H(bbA, Fn, cur);
    __syncthreads();                 // A staged; drains prev-iter epi-B stores
    SETF(flgB, s);
    MFMA_GATES(Bq, KIE);
    __syncthreads();                 // gates A ready; A_lds free
    POLL(flgB, s);
    STAGE_X(bbB, s);
    STAGE_H(bbB, Fn, cur);
    EPI(cA, bie, bfe, bge, boe, bbA, nxt);
    __syncthreads();                 // B staged; drains epi-A stores
    SETF(flgA, s + 1);
    MFMA_GATES(Bq, KIE);
    __syncthreads();                 // gates B ready
    EPI(cB, bie, bfe, bge, boe, bbB, nxt);
  }

  // ================= decoder =================
  cA = 0.f; cB = 0.f;                // reference restarts c at zero
  for (int sd = 0; sd < Tn; ++sd) {
    const int phg = Tn + sd;
    const int cur = phg & 1, nxt = cur ^ 1;
    POLL(flgA, phg);
    STAGE_H(bbA, 0, cur);
    __syncthreads();
    SETF(flgB, phg);
    MFMA_GATES_Y(Bd, yA, bbA, sd);
    __syncthreads();
    POLL(flgB, phg);
    STAGE_H(bbB, 0, cur);
    EPI(cA, bid, bfd, bgd, bod, bbA, nxt);
    __syncthreads();
    SETF(flgA, phg + 1);
    MFMA_GATES_Y(Bd, yB, bbB, sd);
    __syncthreads();
    EPI(cB, bid, bfd, bgd, bod, bbB, nxt);
  }
}

extern "C" void kernel_launch(void* const* d_in, const int* in_sizes, int n_in,
                              void* d_out, int out_size, void* d_ws, size_t ws_size,
                              hipStream_t stream) {
  const float* ts   = (const float*)d_in[0];
  const float* eWih = (const float*)d_in[1];
  const float* eWhh = (const float*)d_in[2];
  const float* ebih = (const float*)d_in[3];
  const float* ebhh = (const float*)d_in[4];
  const float* dWih = (const float*)d_in[5];
  const float* dWhh = (const float*)d_in[6];
  const float* dbih = (const float*)d_in[7];
  const float* dbhh = (const float*)d_in[8];
  const float* Wo   = (const float*)d_in[9];
  const float* bo   = (const float*)d_in[10];
  float* outp = (float*)d_out;

  char* ws = (char*)d_ws;
  unsigned short* Bpe  = (unsigned short*)(ws);                 // 2,621,440 B
  unsigned short* Bpd  = (unsigned short*)(ws + 2621440);       // 2,097,152 B
  unsigned short* Bpw  = (unsigned short*)(ws + 4718592);       //   131,072 B
  float*          benc = (float*)(ws + 4849664);                //     8,192 B
  float*          bdec = (float*)(ws + 4857856);                //     8,192 B
  unsigned short* Hg   = (unsigned short*)(ws + 4866048);       // 1,048,576 B
  unsigned*       flgA = (unsigned*)(ws + 5914624);             //    32,768 B
  unsigned*       flgB = (unsigned*)(ws + 5947392);             //    32,768 B
  unsigned short* xp   = (unsigned short*)(ws + 5980160);       // 16,777,216 B

  pack_enc_k<<<128 * KIE, 64, 0, stream>>>(eWih, eWhh, Bpe);
  pack_dec_k<<<128 * KID, 64, 0, stream>>>(dWih, dWhh, Wo, Bpd);
  pack_wo_k<<<8 * KID, 64, 0, stream>>>(Wo, Bpw);
  bias_k<<<8, 256, 0, stream>>>(ebih, ebhh, dbih, dbhh, dWih, bo, benc, bdec);
  pack_x_k<<<16384, 256, 0, stream>>>(ts, xp);
  init_k<<<256, 256, 0, stream>>>((unsigned long long*)Hg, flgA, flgB);

  lstm_persist<<<NWG, 512, 0, stream>>>(xp, Bpe, Bpd, Bpw, benc, bdec, bo, Hg, flgA, flgB, outp);
}